// Round 5
// baseline (128.002 us; speedup 1.0000x reference)
//
#include <hip/hip_runtime.h>
#include <hip/hip_fp16.h>
#include <stdint.h>

// ---------------------------------------------------------------------------
// ThreeBodyLayer fused kernel v11 (MI355X / gfx950)
//
// All-f16 MFMA pipeline, log2-domain softplus. Scale algebra: W1/b1 carry
// log2(e); W2 carries ln2*log2(e)=1; b2*L2E; W3*LN2.
//
// v11 vs v10 (42.3us, VALU 47%, occ 65%, 2x 16-wave blocks/CU in barrier
// lockstep; ~50% issue-idle at full occupancy):
//  - W1 LDS staging DELETED. prep stores W1 f16 in exact MFMA fragment
//    order (frag-chunk-major, lanes contiguous -> 1KB coalesced wave reads);
//    phase-1 A-frags load straight from ws: same addresses across all
//    blocks -> L2-broadcast (~218MB over kernel ~= 18% L2 BW, 0 HBM).
//  - LDS = T(16x1664) + yred = 26.8KB; BPB 32->16, NT 1024->512
//    => FOUR independent 8-wave blocks/CU (still 32 waves = full occupancy,
//    fixing v9's mistake of dropping to 24). Finer barrier groups + 4
//    decorrelated schedules per CU fill convergence bubbles.
//  - ONE barrier total (was 2): no staging to wait for; yred zeroed before
//    the phase-1->phase-2 barrier.
//  - Keep (validated): ws prep (fill is sunk cost, v7), operand-swapped
//    phase-1 MFMA + packed b64 C-writes + b1-in-C-init (v10), du-hoist,
//    b2-in-C-init, T chunk-swizzle, fully-inline code, RNE converts.
// ---------------------------------------------------------------------------

typedef __attribute__((ext_vector_type(8))) _Float16 f16x8;
typedef __attribute__((ext_vector_type(2))) __fp16   fp16v2;   // cvt_pkrtz ret
typedef __attribute__((ext_vector_type(4))) float    f32x4;
typedef __attribute__((ext_vector_type(4))) unsigned int u32x4;

constexpr int   BPB       = 16;       // batch elems per block
constexpr int   NT        = 512;      // 8 waves
constexpr int   T_STRIDE  = 1664;     // 13 rows * 128 B, chunk-swizzled
constexpr int   Y_OFF     = BPB * T_STRIDE;       // 26624
constexpr int   LDS_BYTES = Y_OFF + 128;          // 26752 -> 4 blocks/CU (wave-capped)

// d_ws layout (bytes)
constexpr int   WS_W1F   = 0;         // 24576: f16 W1 in MFMA frag order
constexpr int   WS_W2T   = 24576;     //  4096: f16 [m=32][k=64]
constexpr int   WS_B1    = 28672;     //   256: f32 b1*L2E
constexpr int   WS_B2    = 28928;     //   128: f32 b2*L2E
constexpr int   WS_W3    = 29056;     //   128: f32 W3*LN2

constexpr float L2E = 1.4426950408889634f;
constexpr float LN2 = 0.6931471805599453f;

// PAIRS i/j packed 3 bits per pair (15 pairs)
constexpr unsigned long long I_BITS =
  (0ull<<0)|(0ull<<3)|(0ull<<6)|(0ull<<9)|(0ull<<12)|
  (1ull<<15)|(1ull<<18)|(1ull<<21)|(1ull<<24)|
  (2ull<<27)|(2ull<<30)|(2ull<<33)|
  (3ull<<36)|(3ull<<39)|(4ull<<42);
constexpr unsigned long long J_BITS =
  (1ull<<0)|(2ull<<3)|(3ull<<6)|(4ull<<9)|(5ull<<12)|
  (2ull<<15)|(3ull<<18)|(4ull<<21)|(5ull<<24)|
  (3ull<<27)|(4ull<<30)|(5ull<<33)|
  (4ull<<36)|(5ull<<39)|(5ull<<42);

__device__ __forceinline__ float sp2(float s) {       // log2(1+exp2(s))
  float t = __builtin_amdgcn_exp2f(s);
  return __builtin_amdgcn_logf(1.0f + t);             // v_log_f32 = log2
}

__device__ __forceinline__ __half2 h1pair(__half2 u, __half2 a, __half2 b,
                                          __half2 one2) {
  __half2 s = __hadd2(__hadd2(u, a), b);
  __half2 t = h2exp2(s);                              // |s|<~8 -> safe in f16
  return h2log2(__hadd2(one2, t));
}

// ------------------------- prep: weights -> d_ws ---------------------------
__global__ __launch_bounds__(256)
void prep(const float* __restrict__ W1, const float* __restrict__ b1,
          const float* __restrict__ W2, const float* __restrict__ b2,
          const float* __restrict__ W3, char* __restrict__ ws)
{
  const int t = (int)(blockIdx.x * blockDim.x + threadIdx.x);   // 0..14591
  if (t < 12288) {
    // W1F frag image, element index t = sl*4096 + nt*1024 + ks*512
    //                                  + qd*128 + ln*8 + e
    // value = W1[dg][n]*L2E with dg = sl*64+ks*32+qd*8+e, n = nt*16+ln.
    const int e  = t & 7;
    const int ln = (t >> 3) & 15;
    const int qd = (t >> 7) & 3;
    const int ks = (t >> 9) & 1;
    const int nt = (t >> 10) & 3;
    const int sl = t >> 12;
    const int dg = sl * 64 + ks * 32 + qd * 8 + e;
    const int n  = nt * 16 + ln;
    ((uint16_t*)(ws + WS_W1F))[t] =
        __half_as_ushort(__float2half(W1[(size_t)dg * 64 + n] * L2E));
  } else if (t < 14336) {
    const int e = t - 12288;                          // W2 is [k=64][m=32]
    const int k = e >> 5, m = e & 31;
    *(uint16_t*)(ws + WS_W2T + (m * 64 + k) * 2) =
        __half_as_ushort(__float2half(W2[e]));
  } else if (t < 14400) {
    ((float*)(ws + WS_B1))[t - 14336] = b1[t - 14336] * L2E;
  } else if (t < 14432) {
    ((float*)(ws + WS_B2))[t - 14400] = b2[t - 14400] * L2E;
  } else if (t < 14464) {
    ((float*)(ws + WS_W3))[t - 14432] = W3[t - 14432] * LN2;
  }
}

// ------------------------------ main kernel --------------------------------
__global__ __launch_bounds__(NT, 8)
void tb_fused(const float* __restrict__ core, const float* __restrict__ ligs,
              const char* __restrict__ ws,   const float* __restrict__ b3,
              float* __restrict__ out)
{
  extern __shared__ char smem[];
  const int tid  = (int)threadIdx.x;
  const int lane = tid & 63;
  const int ln   = lane & 15;        // fragment column
  const int qd   = lane >> 4;        // fragment quad
  const int swz  = ln & 7;           // XOR chunk swizzle key
  const int wv   = __builtin_amdgcn_readfirstlane(tid >> 6);  // 0..7
  const int b0   = (int)blockIdx.x * BPB;

  float* yred = (float*)(smem + Y_OFF);

  // ---- Phase-1 job table: 13 T-rows (0=core, 1..6=slab1, 7..12=slab2) ----
  // Wave w owns rows t1=w and t2=w+8 (t2 valid for w<5).
  const int t1 = wv;
  const int t2 = wv + 8;
  const bool j2 = (wv < 5);

  // x-tile global prefetch (cold HBM): issue first.
  float4 fA[2][4];
  {
    const int xr = (t1 == 0) ? 0 : (t1 <= 6 ? t1 : t1 - 6);
    const float* src = (xr == 0)
        ? (core + (size_t)(b0 + ln) * 64)
        : (ligs + ((size_t)(b0 + ln) * 6 + (size_t)(xr - 1)) * 64);
    #pragma unroll
    for (int ks = 0; ks < 2; ++ks) {
      fA[0][ks * 2 + 0] = *(const float4*)(src + ks * 32 + qd * 8);
      fA[0][ks * 2 + 1] = *(const float4*)(src + ks * 32 + qd * 8 + 4);
    }
  }
  if (j2) {
    const int xr = t2 - 6;                            // 2..6, slab 2
    const float* src = ligs + ((size_t)(b0 + ln) * 6 + (size_t)(xr - 1)) * 64;
    #pragma unroll
    for (int ks = 0; ks < 2; ++ks) {
      fA[1][ks * 2 + 0] = *(const float4*)(src + ks * 32 + qd * 8);
      fA[1][ks * 2 + 1] = *(const float4*)(src + ks * 32 + qd * 8 + 4);
    }
  }
  if (tid < BPB) yred[tid] = 0.0f;

  // Convert x tiles to f16 frags (B operand).
  union AFr { f16x8 v; fp16v2 p[4]; } Xf[2][2];
  #pragma unroll
  for (int jj = 0; jj < 2; ++jj) {
    if (jj == 1 && !j2) break;                        // wave-uniform
    #pragma unroll
    for (int ks = 0; ks < 2; ++ks) {
      Xf[jj][ks].p[0] = __builtin_amdgcn_cvt_pkrtz(fA[jj][ks*2].x, fA[jj][ks*2].y);
      Xf[jj][ks].p[1] = __builtin_amdgcn_cvt_pkrtz(fA[jj][ks*2].z, fA[jj][ks*2].w);
      Xf[jj][ks].p[2] = __builtin_amdgcn_cvt_pkrtz(fA[jj][ks*2+1].x, fA[jj][ks*2+1].y);
      Xf[jj][ks].p[3] = __builtin_amdgcn_cvt_pkrtz(fA[jj][ks*2+1].z, fA[jj][ks*2+1].w);
    }
  }

  // ------------- Phase 1: up to 2 T-row jobs per wave, W1 frags from L2 ---
  #pragma unroll
  for (int jj = 0; jj < 2; ++jj) {
    if (jj == 1 && !j2) break;                        // wave-uniform
    const int t  = (jj == 0) ? t1 : t2;               // trow
    const int sl = (t == 0) ? 0 : (t <= 6 ? 1 : 2);
    #pragma unroll
    for (int nt = 0; nt < 4; ++nt) {
      // D row = n (H1), col = batch: b1 folds into C-init (t=0 only).
      f32x4 c;
      if (t == 0) {
        c = *(const f32x4*)(ws + WS_B1 + (nt * 16 + qd * 4) * 4);
      } else {
        c = (f32x4){0.f, 0.f, 0.f, 0.f};
      }
      #pragma unroll
      for (int ks = 0; ks < 2; ++ks) {
        // A = W1 frag from ws (frag-ordered, lanes contiguous, L2-hot)
        const f16x8 Wf = *(const f16x8*)(ws + WS_W1F
            + (size_t)(sl * 4096 + nt * 1024 + ks * 512 + qd * 128 + ln * 8) * 2);
        c = __builtin_amdgcn_mfma_f32_16x16x32_f16(Wf, Xf[jj][ks].v, c, 0, 0, 0);
      }
      // c[0..3] = consecutive n = nt*16+qd*4+reg, batch col b = ln.
      // One b64 write: off = t*128 + ((2nt+(qd>>1))^swz)*16 + (qd&1)*8
      union PK { uint2 u; __half2 h[2]; } pk;
      pk.h[0] = __halves2half2(__float2half(c[0]), __float2half(c[1]));
      pk.h[1] = __halves2half2(__float2half(c[2]), __float2half(c[3]));
      *(uint2*)(smem + (size_t)ln * T_STRIDE + t * 128
                + ((((nt << 1) + (qd >> 1)) ^ swz) << 4) + (qd & 1) * 8) = pk.u;
    }
  }

  // W2 B-frags + epilogue consts from ws (pre-converted, L2-hot) —
  // overlaps Phase-1 tail.
  f16x8 W2f[2][2];
  #pragma unroll
  for (int nt = 0; nt < 2; ++nt)
    #pragma unroll
    for (int ks = 0; ks < 2; ++ks)
      W2f[nt][ks] = *(const f16x8*)(ws + WS_W2T
          + ((nt * 16 + ln) * 64 + ks * 32 + qd * 8) * 2);
  float b2v[2], w3v[2];
  #pragma unroll
  for (int nt = 0; nt < 2; ++nt) {
    b2v[nt] = ((const float*)(ws + WS_B2))[nt * 16 + ln];
    w3v[nt] = ((const float*)(ws + WS_W3))[nt * 16 + ln];
  }

  __syncthreads();                                    // the ONLY barrier: T ready

  // ------------- Phase 2: 30 q-units over 8 waves -------------------------
  const int qr = wv;                                  // 0..7
  const __half2 one2 = __float2half2_rn(1.0f);
  const char* Tb = smem + (size_t)ln * T_STRIDE;
  const int k0 = ((qd)     ^ swz) << 4;               // chunk qd   (ks=0)
  const int k1 = ((qd + 4) ^ swz) << 4;               // chunk qd+4 (ks=1)

  union U4 { u32x4 u; __half2 h[4]; };

  // Row 0 (core pre-activations) is unit-invariant: hoist its 2 reads.
  U4 du0, du1;
  du0.u = *(const u32x4*)(Tb + k0);
  du1.u = *(const u32x4*)(Tb + k1);

  float yacc[4] = {0.f, 0.f, 0.f, 0.f};

  #pragma unroll 2
  for (int t3 = 0; t3 < 4; ++t3) {
    const int q = qr + 8 * t3;
    if (q >= 30) break;                               // wave-uniform
    const int p  = q >> 1;
    const int iv = (int)((I_BITS >> (3 * p)) & 7ull);
    const int jv = (int)((J_BITS >> (3 * p)) & 7ull);
    const int An = (q & 1) ? jv : iv;
    const int Bn = (q & 1) ? iv : jv;
    const char* TA = Tb + (1 + An) * 128;
    const char* TB = Tb + (7 + Bn) * 128;

    U4 da0, db0, da1, db1;
    da0.u = *(const u32x4*)(TA + k0);
    db0.u = *(const u32x4*)(TB + k0);
    da1.u = *(const u32x4*)(TA + k1);
    db1.u = *(const u32x4*)(TB + k1);

    union { f16x8 v; __half2 h[4]; } A0, A1;
    #pragma unroll
    for (int w = 0; w < 4; ++w) A0.h[w] = h1pair(du0.h[w], da0.h[w], db0.h[w], one2);
    #pragma unroll
    for (int w = 0; w < 4; ++w) A1.h[w] = h1pair(du1.h[w], da1.h[w], db1.h[w], one2);

    f32x4 c0 = {b2v[0], b2v[0], b2v[0], b2v[0]};      // bias as C-init
    f32x4 c1 = {b2v[1], b2v[1], b2v[1], b2v[1]};
    c0 = __builtin_amdgcn_mfma_f32_16x16x32_f16(A0.v, W2f[0][0], c0, 0, 0, 0);
    c0 = __builtin_amdgcn_mfma_f32_16x16x32_f16(A1.v, W2f[0][1], c0, 0, 0, 0);
    c1 = __builtin_amdgcn_mfma_f32_16x16x32_f16(A0.v, W2f[1][0], c1, 0, 0, 0);
    c1 = __builtin_amdgcn_mfma_f32_16x16x32_f16(A1.v, W2f[1][1], c1, 0, 0, 0);

    #pragma unroll
    for (int reg = 0; reg < 4; ++reg) {
      yacc[reg] += sp2(c0[reg]) * w3v[0] + sp2(c1[reg]) * w3v[1];
    }
  }

  // reduce over the 16 fragment columns (ln) inside each quad group
  #pragma unroll
  for (int reg = 0; reg < 4; ++reg) {
    float v = yacc[reg];
    v += __shfl_xor(v, 1);
    v += __shfl_xor(v, 2);
    v += __shfl_xor(v, 4);
    v += __shfl_xor(v, 8);
    yacc[reg] = v;
  }
  if (ln == 0) {
    #pragma unroll
    for (int reg = 0; reg < 4; ++reg)
      atomicAdd(&yred[qd * 4 + reg], yacc[reg]);
  }
  __syncthreads();
  if (tid < BPB) out[b0 + tid] = 0.5f * yred[tid] + 15.0f * b3[0];
}

extern "C" void kernel_launch(void* const* d_in, const int* in_sizes, int n_in,
                              void* d_out, int out_size, void* d_ws, size_t ws_size,
                              hipStream_t stream) {
  const float* core = (const float*)d_in[0];
  const float* ligs = (const float*)d_in[1];
  const float* W1   = (const float*)d_in[2];
  const float* b1   = (const float*)d_in[3];
  const float* W2   = (const float*)d_in[4];
  const float* b2   = (const float*)d_in[5];
  const float* W3   = (const float*)d_in[6];
  const float* b3   = (const float*)d_in[7];
  float* out = (float*)d_out;
  char*  ws  = (char*)d_ws;                 // 29 KB used; fill is sunk cost

  const int B = in_sizes[0] / 64;           // 32768
  const int grid = B / BPB;                 // 2048

  prep<<<dim3(57), dim3(256), 0, stream>>>(W1, b1, W2, b2, W3, ws);

  (void)hipFuncSetAttribute((const void*)tb_fused,
                            hipFuncAttributeMaxDynamicSharedMemorySize, LDS_BYTES);
  tb_fused<<<dim3(grid), dim3(NT), LDS_BYTES, stream>>>(
      core, ligs, ws, b3, out);
}